// Round 2
// baseline (435.352 us; speedup 1.0000x reference)
//
#include <hip/hip_runtime.h>
#include <hip/hip_cooperative_groups.h>

namespace cg = cooperative_groups;

// InformPooling, fused two-phase chunk-sum scheme (cooperative launch).
//   value0 [8,16384,128] r=1.0 ; value1 [8,8192,128] r=0.5 ; value2 [8,4096,256] r=0.25
//   start/duration [8,512]; out [8,512,512] f32 (channels concat 128|128|256).
//
// Phase 1 (chunk sums): stream v once, write sums of C=8 rows into d_ws.
//   S0 [8][2048][128], S1 [8][1024][128], S2 [8][512][256]  -> 16.8 MB (LLC-hot).
// grid.sync()
// Phase 2 (gather): per (bn,pool) wave: interior = chunk reads from S (1KB pair loads),
//   edges = pair-row reads from v; xor-32 reduce; store.
// Fusing removes one launch + inter-kernel drain per iteration and makes the single
// dispatch duration reveal phase-2's cost in the profile.

constexpr int   kB   = 8;
constexpr int   kN   = 512;
constexpr float kEps = 1e-3f;
constexpr int   kC   = 8;  // chunk rows

// float offsets into ws
constexpr size_t S0_OFF = 0;                       // 8*2048*128
constexpr size_t S1_OFF = (size_t)8 * 2048 * 128;  // + 8*1024*128
constexpr size_t S2_OFF = S1_OFF + (size_t)8 * 1024 * 128;

__device__ __forceinline__ void acc4(float4& a, const float4 x) {
    a.x += x.x; a.y += x.y; a.z += x.z; a.w += x.w;
}

__device__ __forceinline__ float4 xor32_add(float4 a) {
    a.x += __shfl_xor(a.x, 32);
    a.y += __shfl_xor(a.y, 32);
    a.z += __shfl_xor(a.z, 32);
    a.w += __shfl_xor(a.w, 32);
    return a;
}

// ---- phase 1 body: one wave-unit = one chunk-pair (pools 0/1) or one chunk (pool 2)
__device__ __forceinline__ void pass1_unit(int w, int lane,
    const float* __restrict__ v0, const float* __restrict__ v1,
    const float* __restrict__ v2, float* __restrict__ ws)
{
    if (w < 8192) {                        // pool0: b*1024 chunk-PAIRS (16 rows = 8KB)
        const int b = w >> 10, pr = w & 1023;
        const float4* p = (const float4*)v0
            + ((size_t)b * 16384 + (size_t)pr * 16) * 32 + lane;
        float4 a0 = make_float4(0.f, 0.f, 0.f, 0.f);
        float4 a1 = make_float4(0.f, 0.f, 0.f, 0.f);
#pragma unroll
        for (int j = 0; j < 4; j++) acc4(a0, p[j * 64]);
#pragma unroll
        for (int j = 4; j < 8; j++) acc4(a1, p[j * 64]);
        a0 = xor32_add(a0);
        a1 = xor32_add(a1);
        float4 v = (lane < 32) ? a0 : a1;
        ((float4*)(ws + S0_OFF))[((size_t)b * 2048 + (size_t)pr * 2) * 32 + lane] = v;
    } else if (w < 12288) {                // pool1: b*512 chunk-pairs
        const int idx = w - 8192;
        const int b = idx >> 9, pr = idx & 511;
        const float4* p = (const float4*)v1
            + ((size_t)b * 8192 + (size_t)pr * 16) * 32 + lane;
        float4 a0 = make_float4(0.f, 0.f, 0.f, 0.f);
        float4 a1 = make_float4(0.f, 0.f, 0.f, 0.f);
#pragma unroll
        for (int j = 0; j < 4; j++) acc4(a0, p[j * 64]);
#pragma unroll
        for (int j = 4; j < 8; j++) acc4(a1, p[j * 64]);
        a0 = xor32_add(a0);
        a1 = xor32_add(a1);
        float4 v = (lane < 32) ? a0 : a1;
        ((float4*)(ws + S1_OFF))[((size_t)b * 1024 + (size_t)pr * 2) * 32 + lane] = v;
    } else if (w < 16384) {                // pool2: b*512 chunks, 256 ch (1KB rows)
        const int idx = w - 12288;
        const int b = idx >> 9, tc = idx & 511;
        const float4* p = (const float4*)v2
            + ((size_t)b * 4096 + (size_t)tc * kC) * 64 + lane;
        float4 a0 = make_float4(0.f, 0.f, 0.f, 0.f);
        float4 a1 = make_float4(0.f, 0.f, 0.f, 0.f);
#pragma unroll
        for (int i = 0; i < 4; i++) acc4(a0, p[i * 64]);
#pragma unroll
        for (int i = 4; i < 8; i++) acc4(a1, p[i * 64]);
        acc4(a0, a1);
        ((float4*)(ws + S2_OFF))[((size_t)b * 512 + (size_t)tc) * 64 + lane] = a0;
    }
}

// ---- phase 2 body: one wave-unit = one (bn, pool) output segment
__device__ __forceinline__ void pass2_unit(int unit, int lane,
    const float* __restrict__ v0, const float* __restrict__ v1,
    const float* __restrict__ v2, const float* __restrict__ start,
    const float* __restrict__ dur, const float* __restrict__ ws,
    float* __restrict__ out)
{
    const int bn   = unit / 3;          // [0, 4096)
    const int pool = unit - bn * 3;
    const int b    = bn >> 9;
    const int lane_lo = lane & 31;
    const int hi      = lane >> 5;

    const float st = start[bn];
    const float du = dur[bn];
    float* outbase = out + (size_t)bn * 512;

    if (pool < 2) {
        const float*  v  = (pool == 0) ? v0 : v1;
        const float*  S  = ws + ((pool == 0) ? S0_OFF : S1_OFF);
        const int     T  = (pool == 0) ? 16384 : 8192;
        const int     NC = T / kC;
        const float   r  = (pool == 0) ? 1.0f : 0.5f;
        const int s = min((int)floorf(st * r), T - 1);
        const int e = min((int)ceilf((st + du + kEps) * r), T - 1);
        const int cnt = e - s;

        float4 a0 = make_float4(0.f, 0.f, 0.f, 0.f);
        float4 a1 = make_float4(0.f, 0.f, 0.f, 0.f);
        if (cnt > 0) {
            // row t occupies float4s [t*32, t*32+32); pair load: lane<32 row t, lane>=32 row t+1
            const float4* vp = (const float4*)v + (size_t)b * T * 32;
            const int cs = (s + kC - 1) >> 3;
            const int ce = e >> 3;
            if (ce > cs) {
                const float4* Sp = (const float4*)S + (size_t)b * NC * 32;
                int c = cs;
                for (; c + 4 <= ce; c += 4) {                  // interior, 4 chunks/iter
                    acc4(a0, Sp[(size_t)c * 32 + lane]);
                    acc4(a1, Sp[(size_t)(c + 2) * 32 + lane]);
                }
                if (c + 2 <= ce) { acc4(a0, Sp[(size_t)c * 32 + lane]); c += 2; }
                if (c < ce) {                                  // odd tail chunk: hi half masked
                    float4 x = Sp[(size_t)c * 32 + lane];
                    if (hi == 0) acc4(a0, x);
                }
                const int fe = cs << 3;
                for (int t = s; t < fe; t += 2) {              // front edge (<=7 rows)
                    float4 x = vp[(size_t)t * 32 + lane];
                    if (hi == 0 || t + 1 < fe) acc4(a0, x);
                }
                const int be = ce << 3;
                for (int t = be; t < e; t += 2) {              // back edge (<=7 rows)
                    float4 x = vp[(size_t)t * 32 + lane];
                    if (hi == 0 || t + 1 < e) acc4(a1, x);
                }
            } else {
                for (int t = s; t < e; t += 2) {               // short segment (<=15 rows)
                    float4 x = vp[(size_t)t * 32 + lane];
                    if (hi == 0 || t + 1 < e) acc4(a0, x);
                }
            }
        }
        float4 res = make_float4(0.f, 0.f, 0.f, 0.f);
        if (cnt > 0) {
            acc4(a0, a1);
            a0 = xor32_add(a0);                                // fold row-t / row-t+1 halves
            const float inv = 1.0f / (float)cnt;
            res.x = a0.x * inv; res.y = a0.y * inv;
            res.z = a0.z * inv; res.w = a0.w * inv;
        }
        if (hi == 0)
            ((float4*)(outbase + (pool == 0 ? 0 : 128)))[lane_lo] = res;
    } else {
        const int   T  = 4096;
        const int   NC = T / kC;
        const float r  = 0.25f;
        const int s = min((int)floorf(st * r), T - 1);
        const int e = min((int)ceilf((st + du + kEps) * r), T - 1);
        const int cnt = e - s;

        float4 a0 = make_float4(0.f, 0.f, 0.f, 0.f);
        float4 a1 = make_float4(0.f, 0.f, 0.f, 0.f);
        if (cnt > 0) {
            const float4* vp = (const float4*)v2 + (size_t)b * T * 64 + lane;
            const int cs = (s + kC - 1) >> 3;
            const int ce = e >> 3;
            if (ce > cs) {
                const float4* Sp = (const float4*)(ws + S2_OFF) + (size_t)b * NC * 64 + lane;
                int c = cs;
                for (; c + 4 <= ce; c += 4) {                  // interior, 4 chunks/iter
                    acc4(a0, Sp[(size_t)c * 64]);
                    acc4(a1, Sp[(size_t)(c + 1) * 64]);
                    acc4(a0, Sp[(size_t)(c + 2) * 64]);
                    acc4(a1, Sp[(size_t)(c + 3) * 64]);
                }
                for (; c < ce; ++c) acc4(a0, Sp[(size_t)c * 64]);
                for (int t = s; t < cs * kC; ++t) acc4(a0, vp[(size_t)t * 64]);
                for (int t = ce * kC; t < e; ++t) acc4(a1, vp[(size_t)t * 64]);
            } else {
                for (int t = s; t < e; ++t) acc4(a0, vp[(size_t)t * 64]);
            }
        }
        float4 res = make_float4(0.f, 0.f, 0.f, 0.f);
        if (cnt > 0) {
            acc4(a0, a1);
            const float inv = 1.0f / (float)cnt;
            res.x = a0.x * inv; res.y = a0.y * inv;
            res.z = a0.z * inv; res.w = a0.w * inv;
        }
        ((float4*)(outbase + 256))[lane] = res;
    }
}

// ---- fused cooperative kernel
__global__ __launch_bounds__(256) void fused_kernel(
    const float* __restrict__ v0, const float* __restrict__ v1,
    const float* __restrict__ v2, const float* __restrict__ start,
    const float* __restrict__ dur, float* __restrict__ ws,
    float* __restrict__ out)
{
    const int gw   = (int)((blockIdx.x * blockDim.x + threadIdx.x) >> 6);
    const int nw   = (int)((gridDim.x * blockDim.x) >> 6);
    const int lane = threadIdx.x & 63;

    for (int u = gw; u < 16384; u += nw)
        pass1_unit(u, lane, v0, v1, v2, ws);

    __threadfence();                 // device-scope: ws visible across XCDs
    cg::this_grid().sync();

    for (int u = gw; u < 12288; u += nw)
        pass2_unit(u, lane, v0, v1, v2, start, dur, ws, out);
}

// ---- fallback two-kernel path (proven R1 structure)
__global__ __launch_bounds__(256) void chunk_sum_kernel(
    const float* __restrict__ v0, const float* __restrict__ v1,
    const float* __restrict__ v2, float* __restrict__ ws)
{
    const int w    = (blockIdx.x * 256 + threadIdx.x) >> 6;
    const int lane = threadIdx.x & 63;
    pass1_unit(w, lane, v0, v1, v2, ws);
}

__global__ __launch_bounds__(256) void gather_kernel(
    const float* __restrict__ v0, const float* __restrict__ v1,
    const float* __restrict__ v2, const float* __restrict__ start,
    const float* __restrict__ dur, const float* __restrict__ ws,
    float* __restrict__ out)
{
    const int wave = threadIdx.x >> 6;
    const int lane = threadIdx.x & 63;
    const int bn   = blockIdx.x * 4 + wave;
    const int pool = blockIdx.y;
    pass2_unit(bn * 3 + pool, lane, v0, v1, v2, start, dur, ws, out);
}

extern "C" void kernel_launch(void* const* d_in, const int* in_sizes, int n_in,
                              void* d_out, int out_size, void* d_ws, size_t ws_size,
                              hipStream_t stream) {
    const float* v0    = (const float*)d_in[0];
    const float* v1    = (const float*)d_in[1];
    const float* v2    = (const float*)d_in[2];
    const float* start = (const float*)d_in[3];
    const float* dur   = (const float*)d_in[4];
    float*       out   = (float*)d_out;
    float*       ws    = (float*)d_ws;

    static int coop_state  = -1;   // -1 unknown, 0 no, 1 yes
    static int grid_blocks = 0;

    if (coop_state < 0) {
        int dev = 0, attr = 0, ncu = 0, occ = 0;
        (void)hipGetDevice(&dev);
        (void)hipDeviceGetAttribute(&attr, hipDeviceAttributeCooperativeLaunch, dev);
        (void)hipDeviceGetAttribute(&ncu, hipDeviceAttributeMultiprocessorCount, dev);
        (void)hipOccupancyMaxActiveBlocksPerMultiprocessor(&occ, fused_kernel, 256, 0);
        if (attr > 0 && ncu > 0 && occ > 0) {
            int gb = occ * ncu;
            if (gb > 3072) gb = 3072;   // >= work would be idle
            grid_blocks = gb;
            coop_state  = 1;
        } else {
            coop_state = 0;
        }
    }

    if (coop_state == 1) {
        void* args[] = { (void*)&v0, (void*)&v1, (void*)&v2,
                         (void*)&start, (void*)&dur, (void*)&ws, (void*)&out };
        hipError_t e = hipLaunchCooperativeKernel((const void*)fused_kernel,
                                                  dim3(grid_blocks), dim3(256),
                                                  args, 0, stream);
        if (e == hipSuccess) return;
        coop_state = 0;   // fall through to two-kernel path
    }

    chunk_sum_kernel<<<dim3(16384 / 4), 256, 0, stream>>>(v0, v1, v2, ws);
    gather_kernel<<<dim3(kB * kN / 4, 3), 256, 0, stream>>>(v0, v1, v2, start, dur, ws, out);
}

// Round 3
// 178.212 us; speedup vs baseline: 2.4429x; 2.4429x over previous
//
#include <hip/hip_runtime.h>

// InformPooling, two-pass scheme with within-superchunk prefix sums.
//   value0 [8,16384,128] r=1.0 ; value1 [8,8192,128] r=0.5 ; value2 [8,4096,256] r=0.25
//   start/duration [8,512]; out [8,512,512] f32 (channels concat 128|128|256).
//
// Pass 1 (prefix): stream v once. Each wave owns one SUPERCHUNK (pools0/1: 64 rows =
//   8 chunks of 8; pool2: 32 rows = 4 chunks) and writes the INCLUSIVE prefix of its
//   chunk sums into P (ws). Superchunk totals SS[sc] == P[sc*SCH + SCH-1] — no extra
//   storage. P0 [8][2048][128], P1 [8][1024][128], P2 [8][512][256] = 16.8 MB.
// Pass 2 (gather): interior of [cs,ce) = P[ce-1] - (j(cs)?P[cs-1]:0) + sum of middle
//   superchunk totals (<=5 reads) instead of ~19 chunk reads; edges = <=7 direct rows
//   from v at each end. Gather logical bytes ~143 -> ~93 MB.

constexpr int   kB   = 8;
constexpr int   kN   = 512;
constexpr float kEps = 1e-3f;

// float offsets into ws
constexpr size_t P0_OFF = 0;                                 // [8][2048][128]
constexpr size_t P1_OFF = (size_t)8 * 2048 * 128;            // [8][1024][128]
constexpr size_t P2_OFF = P1_OFF + (size_t)8 * 1024 * 128;   // [8][512][256]

__device__ __forceinline__ void acc4(float4& a, const float4 x) {
    a.x += x.x; a.y += x.y; a.z += x.z; a.w += x.w;
}
__device__ __forceinline__ void acc4w(float4& a, const float4 x, float w) {
    a.x = fmaf(w, x.x, a.x); a.y = fmaf(w, x.y, a.y);
    a.z = fmaf(w, x.z, a.z); a.w = fmaf(w, x.w, a.w);
}
__device__ __forceinline__ void sub4(float4& a, const float4 x) {
    a.x -= x.x; a.y -= x.y; a.z -= x.z; a.w -= x.w;
}
__device__ __forceinline__ float4 xor32_add(float4 a) {
    a.x += __shfl_xor(a.x, 32);
    a.y += __shfl_xor(a.y, 32);
    a.z += __shfl_xor(a.z, 32);
    a.w += __shfl_xor(a.w, 32);
    return a;
}

// ---------------- pass 1: superchunk prefix sums ----------------
// units: pool0 = 2048 (8b x 256 sc of 64 rows), pool1 = 1024 (8b x 128),
//        pool2 = 1024 (8b x 128 sc of 32 rows).  4096 waves total.
__global__ __launch_bounds__(256) void prefix_kernel(
    const float* __restrict__ v0, const float* __restrict__ v1,
    const float* __restrict__ v2, float* __restrict__ ws)
{
    const int w    = (blockIdx.x * 256 + threadIdx.x) >> 6;
    const int lane = threadIdx.x & 63;
    const int hi   = lane >> 5;

    if (w < 3072) {                 // pools 0/1: pair-row layout (lane<32 even row, lane>=32 odd)
        const float* v;  float* Pb;  int T;
        int b, sc;
        if (w < 2048) { b = w >> 8;  sc = w & 255;  v = v0; T = 16384;
                        Pb = ws + P0_OFF + ((size_t)b * 2048 + (size_t)sc * 8) * 128; }
        else { const int idx = w - 2048; b = idx >> 7; sc = idx & 127; v = v1; T = 8192;
               Pb = ws + P1_OFF + ((size_t)b * 1024 + (size_t)sc * 8) * 128; }

        const float4* p = (const float4*)v + ((size_t)b * T + (size_t)sc * 64) * 32 + lane;
        float4 run = make_float4(0.f, 0.f, 0.f, 0.f);
        float4 P[8];
#pragma unroll
        for (int k = 0; k < 4; k++) {           // 2 chunks per batch = 8 pair-loads in flight
            float4 x0 = p[(8 * k + 0) * 64], x1 = p[(8 * k + 1) * 64];
            float4 x2 = p[(8 * k + 2) * 64], x3 = p[(8 * k + 3) * 64];
            float4 x4 = p[(8 * k + 4) * 64], x5 = p[(8 * k + 5) * 64];
            float4 x6 = p[(8 * k + 6) * 64], x7 = p[(8 * k + 7) * 64];
            float4 a0 = x0; acc4(a0, x1); acc4(a0, x2); acc4(a0, x3);
            float4 a1 = x4; acc4(a1, x5); acc4(a1, x6); acc4(a1, x7);
            a0 = xor32_add(a0);                  // chunk sum replicated in both halves
            a1 = xor32_add(a1);
            acc4(run, a0); P[2 * k]     = run;   // inclusive prefix within superchunk
            acc4(run, a1); P[2 * k + 1] = run;
        }
#pragma unroll
        for (int k = 0; k < 4; k++) {           // paired store: lo half chunk 2k, hi half 2k+1
            float4 val = hi ? P[2 * k + 1] : P[2 * k];
            ((float4*)Pb)[(size_t)(2 * k) * 32 + lane] = val;
        }
    } else {                        // pool2: 256 ch, one row per load, superchunk 32 rows
        const int idx = w - 3072;
        const int b = idx >> 7, sc = idx & 127;
        const float4* p = (const float4*)v2 + ((size_t)b * 4096 + (size_t)sc * 32) * 64 + lane;
        float* Pb = ws + P2_OFF + ((size_t)b * 512 + (size_t)sc * 4) * 256;
        float4 run = make_float4(0.f, 0.f, 0.f, 0.f);
#pragma unroll
        for (int k = 0; k < 4; k++) {           // chunk k = rows 8k..8k+7, 8 loads in flight
            float4 a = p[(8 * k) * 64];
#pragma unroll
            for (int j = 1; j < 8; j++) acc4(a, p[(8 * k + j) * 64]);
            acc4(run, a);
            ((float4*)Pb)[(size_t)k * 64 + lane] = run;
        }
    }
}

// ---------------- pass 2: gather via prefix differences ----------------
__global__ __launch_bounds__(256) void gather_kernel(
    const float* __restrict__ v0, const float* __restrict__ v1,
    const float* __restrict__ v2, const float* __restrict__ start,
    const float* __restrict__ dur, const float* __restrict__ ws,
    float* __restrict__ out)
{
    const int wave    = threadIdx.x >> 6;
    const int lane    = threadIdx.x & 63;
    const int lane_lo = lane & 31;
    const int hi      = lane >> 5;
    const int bn      = blockIdx.x * 4 + wave;   // [0, 4096)
    const int b       = bn >> 9;
    const int pool    = blockIdx.y;

    const float st = start[bn];
    const float du = dur[bn];
    float* outbase = out + (size_t)bn * 512;

    if (pool < 2) {
        const float*  v  = (pool == 0) ? v0 : v1;
        const float*  P  = ws + ((pool == 0) ? P0_OFF : P1_OFF);
        const int     T  = (pool == 0) ? 16384 : 8192;
        const int     NC = T / 8;
        const float   r  = (pool == 0) ? 1.0f : 0.5f;
        const int s = min((int)floorf(st * r), T - 1);
        const int e = min((int)ceilf((st + du + kEps) * r), T - 1);
        const int cnt = e - s;

        float4 acc = make_float4(0.f, 0.f, 0.f, 0.f);
        if (cnt > 0) {
            const float4* vp = (const float4*)v + (size_t)b * T * 32;
            const float4* Pb = (const float4*)P + (size_t)b * NC * 32;
            const int cs = (s + 7) >> 3;
            const int ce = e >> 3;
            if (ce > cs) {
                // paired load: lo half = Q-entry, hi half = P[ce-1]
                const int jq = cs & 7;
                const int cq = jq ? cs - 1 : cs;          // dummy (weight 0) when aligned
                const int ilo = cq * 32 + lane_lo;
                const int ihi = (ce - 1) * 32 + lane_lo;
                float4 x = Pb[(size_t)(hi ? ihi : ilo)];
                const float wq = hi ? 1.f : (jq ? -1.f : 0.f);
                acc4w(acc, x, wq);
                // middle superchunk totals SS[m] = P[8m+7], m in [cs>>3, (ce-1)>>3)
                int m  = cs >> 3;
                const int me = (ce - 1) >> 3;
                for (; m + 2 <= me; m += 2) {             // paired, 2 SS per load
                    const int i0 = (m * 8 + 7) * 32 + lane_lo;
                    const int i1 = ((m + 1) * 8 + 7) * 32 + lane_lo;
                    float4 y = Pb[(size_t)(hi ? i1 : i0)];
                    acc4(acc, y);
                }
                if (m < me) {                             // odd tail SS: lo half only
                    float4 y = Pb[(size_t)((m * 8 + 7) * 32 + lane_lo)];
                    acc4w(acc, y, hi ? 0.f : 1.f);
                }
                // edges: pair-row loads with hi-half masking
                const int fe = cs << 3;
                for (int t = s; t < fe; t += 2) {
                    float4 x2 = vp[(size_t)t * 32 + lane];
                    if (hi == 0 || t + 1 < fe) acc4(acc, x2);
                }
                const int be = ce << 3;
                for (int t = be; t < e; t += 2) {
                    float4 x2 = vp[(size_t)t * 32 + lane];
                    if (hi == 0 || t + 1 < e) acc4(acc, x2);
                }
            } else {
                for (int t = s; t < e; t += 2) {          // short segment (<=15 rows)
                    float4 x2 = vp[(size_t)t * 32 + lane];
                    if (hi == 0 || t + 1 < e) acc4(acc, x2);
                }
            }
        }
        float4 res = make_float4(0.f, 0.f, 0.f, 0.f);
        if (cnt > 0) {
            acc = xor32_add(acc);                         // fold halves (P diff + SS + edges)
            const float inv = 1.0f / (float)cnt;
            res.x = acc.x * inv; res.y = acc.y * inv;
            res.z = acc.z * inv; res.w = acc.w * inv;
        }
        if (hi == 0)
            ((float4*)(outbase + (pool == 0 ? 0 : 128)))[lane_lo] = res;
    } else {
        const int   T  = 4096;
        const int   NC = T / 8;
        const float r  = 0.25f;
        const int s = min((int)floorf(st * r), T - 1);
        const int e = min((int)ceilf((st + du + kEps) * r), T - 1);
        const int cnt = e - s;

        float4 acc = make_float4(0.f, 0.f, 0.f, 0.f);
        if (cnt > 0) {
            const float4* vp = (const float4*)v2 + (size_t)b * T * 64 + lane;
            const float4* Pb = (const float4*)(ws + P2_OFF) + (size_t)b * NC * 64 + lane;
            const int cs = (s + 7) >> 3;
            const int ce = e >> 3;
            if (ce > cs) {
                acc = Pb[(size_t)(ce - 1) * 64];          // prefix within superchunk of ce-1
                const int jq = cs & 3;
                if (jq) sub4(acc, Pb[(size_t)(cs - 1) * 64]);
                int m  = cs >> 2;
                const int me = (ce - 1) >> 2;
                for (; m < me; ++m)                       // middle SS[m] = P[4m+3], <=3 iters
                    acc4(acc, Pb[(size_t)(m * 4 + 3) * 64]);
                for (int t = s; t < (cs << 3); ++t) acc4(acc, vp[(size_t)t * 64]);
                for (int t = (ce << 3); t < e; ++t) acc4(acc, vp[(size_t)t * 64]);
            } else {
                for (int t = s; t < e; ++t) acc4(acc, vp[(size_t)t * 64]);
            }
        }
        float4 res = make_float4(0.f, 0.f, 0.f, 0.f);
        if (cnt > 0) {
            const float inv = 1.0f / (float)cnt;
            res.x = acc.x * inv; res.y = acc.y * inv;
            res.z = acc.z * inv; res.w = acc.w * inv;
        }
        ((float4*)(outbase + 256))[lane] = res;
    }
}

extern "C" void kernel_launch(void* const* d_in, const int* in_sizes, int n_in,
                              void* d_out, int out_size, void* d_ws, size_t ws_size,
                              hipStream_t stream) {
    const float* v0    = (const float*)d_in[0];
    const float* v1    = (const float*)d_in[1];
    const float* v2    = (const float*)d_in[2];
    const float* start = (const float*)d_in[3];
    const float* dur   = (const float*)d_in[4];
    float*       out   = (float*)d_out;
    float*       ws    = (float*)d_ws;

    // Pass 1: 4096 waves (2048 + 1024 + 1024), 4 waves/block
    prefix_kernel<<<dim3(4096 / 4), 256, 0, stream>>>(v0, v1, v2, ws);
    // Pass 2: one wave per (bn, pool)
    gather_kernel<<<dim3(kB * kN / 4, 3), 256, 0, stream>>>(v0, v1, v2, start, dur, ws, out);
}

// Round 4
// 169.410 us; speedup vs baseline: 2.5698x; 1.0520x over previous
//
#include <hip/hip_runtime.h>

// InformPooling, two-pass scheme with within-superchunk prefix sums.
//   value0 [8,16384,128] r=1.0 ; value1 [8,8192,128] r=0.5 ; value2 [8,4096,256] r=0.25
//   start/duration [8,512]; out [8,512,512] f32 (channels concat 128|128|256).
//
// Pass 1 (prefix): stream v once. Each wave owns one SUPERCHUNK (pools0/1: 64 rows =
//   8 chunks of 8; pool2: 32 rows = 4 chunks) and writes the INCLUSIVE prefix of its
//   chunk sums into P (ws). Stores issue INSIDE the k-loop — R3 buffered P[8] across
//   the loop and the compiler spilled it to scratch (VGPR=36, WRITE_SIZE +24 MiB =
//   3072 waves x 8 KiB, dur 45->56 us). Superchunk totals SS[sc] = P[sc*SCH+SCH-1].
//   P0 [8][2048][128], P1 [8][1024][128], P2 [8][512][256] = 16.8 MB.
// Pass 2 (gather): interior of [cs,ce) = P[ce-1] - (cs%SCH ? P[cs-1] : 0) + sum of
//   middle superchunk totals (<=5 reads); edges = <=7 direct rows from v at each end.

constexpr int   kB   = 8;
constexpr int   kN   = 512;
constexpr float kEps = 1e-3f;

// float offsets into ws
constexpr size_t P0_OFF = 0;                                 // [8][2048][128]
constexpr size_t P1_OFF = (size_t)8 * 2048 * 128;            // [8][1024][128]
constexpr size_t P2_OFF = P1_OFF + (size_t)8 * 1024 * 128;   // [8][512][256]

__device__ __forceinline__ void acc4(float4& a, const float4 x) {
    a.x += x.x; a.y += x.y; a.z += x.z; a.w += x.w;
}
__device__ __forceinline__ void acc4w(float4& a, const float4 x, float w) {
    a.x = fmaf(w, x.x, a.x); a.y = fmaf(w, x.y, a.y);
    a.z = fmaf(w, x.z, a.z); a.w = fmaf(w, x.w, a.w);
}
__device__ __forceinline__ void sub4(float4& a, const float4 x) {
    a.x -= x.x; a.y -= x.y; a.z -= x.z; a.w -= x.w;
}
__device__ __forceinline__ float4 xor32_add(float4 a) {
    a.x += __shfl_xor(a.x, 32);
    a.y += __shfl_xor(a.y, 32);
    a.z += __shfl_xor(a.z, 32);
    a.w += __shfl_xor(a.w, 32);
    return a;
}

// ---------------- pass 1: superchunk prefix sums ----------------
// units: pool0 = 2048 (8b x 256 sc of 64 rows), pool1 = 1024 (8b x 128),
//        pool2 = 1024 (8b x 128 sc of 32 rows).  4096 waves total.
__global__ __launch_bounds__(256) void prefix_kernel(
    const float* __restrict__ v0, const float* __restrict__ v1,
    const float* __restrict__ v2, float* __restrict__ ws)
{
    const int w    = (blockIdx.x * 256 + threadIdx.x) >> 6;
    const int lane = threadIdx.x & 63;
    const int hi   = lane >> 5;

    if (w < 3072) {                 // pools 0/1: pair-row layout (lane<32 even row, lane>=32 odd)
        const float* v;  float* Pb;  int T;
        int b, sc;
        if (w < 2048) { b = w >> 8;  sc = w & 255;  v = v0; T = 16384;
                        Pb = ws + P0_OFF + ((size_t)b * 2048 + (size_t)sc * 8) * 128; }
        else { const int idx = w - 2048; b = idx >> 7; sc = idx & 127; v = v1; T = 8192;
               Pb = ws + P1_OFF + ((size_t)b * 1024 + (size_t)sc * 8) * 128; }

        const float4* p = (const float4*)v + ((size_t)b * T + (size_t)sc * 64) * 32 + lane;
        float4 run = make_float4(0.f, 0.f, 0.f, 0.f);
#pragma unroll
        for (int k = 0; k < 4; k++) {           // 2 chunks per batch = 8 pair-loads in flight
            float4 x0 = p[(8 * k + 0) * 64], x1 = p[(8 * k + 1) * 64];
            float4 x2 = p[(8 * k + 2) * 64], x3 = p[(8 * k + 3) * 64];
            float4 x4 = p[(8 * k + 4) * 64], x5 = p[(8 * k + 5) * 64];
            float4 x6 = p[(8 * k + 6) * 64], x7 = p[(8 * k + 7) * 64];
            float4 a0 = x0; acc4(a0, x1); acc4(a0, x2); acc4(a0, x3);
            float4 a1 = x4; acc4(a1, x5); acc4(a1, x6); acc4(a1, x7);
            a0 = xor32_add(a0);                  // chunk sum replicated in both halves
            a1 = xor32_add(a1);
            acc4(run, a0); float4 plo = run;     // inclusive prefix, chunk 2k
            acc4(run, a1);                       // inclusive prefix, chunk 2k+1 (== run)
            float4 val = hi ? run : plo;         // paired store: lo half chunk 2k, hi 2k+1
            ((float4*)Pb)[(size_t)(2 * k) * 32 + lane] = val;   // 1 KB contiguous
        }
    } else {                        // pool2: 256 ch, one row per load, superchunk 32 rows
        const int idx = w - 3072;
        const int b = idx >> 7, sc = idx & 127;
        const float4* p = (const float4*)v2 + ((size_t)b * 4096 + (size_t)sc * 32) * 64 + lane;
        float* Pb = ws + P2_OFF + ((size_t)b * 512 + (size_t)sc * 4) * 256;
        float4 run = make_float4(0.f, 0.f, 0.f, 0.f);
#pragma unroll
        for (int k = 0; k < 4; k++) {           // chunk k = rows 8k..8k+7, 8 loads in flight
            float4 a = p[(8 * k) * 64];
#pragma unroll
            for (int j = 1; j < 8; j++) acc4(a, p[(8 * k + j) * 64]);
            acc4(run, a);
            ((float4*)Pb)[(size_t)k * 64 + lane] = run;
        }
    }
}

// ---------------- pass 2: gather via prefix differences ----------------
__global__ __launch_bounds__(256) void gather_kernel(
    const float* __restrict__ v0, const float* __restrict__ v1,
    const float* __restrict__ v2, const float* __restrict__ start,
    const float* __restrict__ dur, const float* __restrict__ ws,
    float* __restrict__ out)
{
    const int wave    = threadIdx.x >> 6;
    const int lane    = threadIdx.x & 63;
    const int lane_lo = lane & 31;
    const int hi      = lane >> 5;
    const int bn      = blockIdx.x * 4 + wave;   // [0, 4096)
    const int b       = bn >> 9;
    const int pool    = blockIdx.y;

    const float st = start[bn];
    const float du = dur[bn];
    float* outbase = out + (size_t)bn * 512;

    if (pool < 2) {
        const float*  v  = (pool == 0) ? v0 : v1;
        const float*  P  = ws + ((pool == 0) ? P0_OFF : P1_OFF);
        const int     T  = (pool == 0) ? 16384 : 8192;
        const int     NC = T / 8;
        const float   r  = (pool == 0) ? 1.0f : 0.5f;
        const int s = min((int)floorf(st * r), T - 1);
        const int e = min((int)ceilf((st + du + kEps) * r), T - 1);
        const int cnt = e - s;

        float4 acc = make_float4(0.f, 0.f, 0.f, 0.f);
        if (cnt > 0) {
            const float4* vp = (const float4*)v + (size_t)b * T * 32;
            const float4* Pb = (const float4*)P + (size_t)b * NC * 32;
            const int cs = (s + 7) >> 3;
            const int ce = e >> 3;
            if (ce > cs) {
                // paired load: lo half = Q-entry (subtract), hi half = P[ce-1]
                const int jq = cs & 7;
                const int cq = jq ? cs - 1 : cs;          // dummy (weight 0) when aligned
                const int ilo = cq * 32 + lane_lo;
                const int ihi = (ce - 1) * 32 + lane_lo;
                float4 x = Pb[(size_t)(hi ? ihi : ilo)];
                const float wq = hi ? 1.f : (jq ? -1.f : 0.f);
                acc4w(acc, x, wq);
                // middle superchunk totals SS[m] = P[8m+7], m in [cs>>3, (ce-1)>>3)
                int m  = cs >> 3;
                const int me = (ce - 1) >> 3;
                for (; m + 2 <= me; m += 2) {             // paired, 2 SS per load
                    const int i0 = (m * 8 + 7) * 32 + lane_lo;
                    const int i1 = ((m + 1) * 8 + 7) * 32 + lane_lo;
                    float4 y = Pb[(size_t)(hi ? i1 : i0)];
                    acc4(acc, y);
                }
                if (m < me) {                             // odd tail SS: lo half only
                    float4 y = Pb[(size_t)((m * 8 + 7) * 32 + lane_lo)];
                    acc4w(acc, y, hi ? 0.f : 1.f);
                }
                // edges: pair-row loads with hi-half masking
                const int fe = cs << 3;
                for (int t = s; t < fe; t += 2) {
                    float4 x2 = vp[(size_t)t * 32 + lane];
                    if (hi == 0 || t + 1 < fe) acc4(acc, x2);
                }
                const int be = ce << 3;
                for (int t = be; t < e; t += 2) {
                    float4 x2 = vp[(size_t)t * 32 + lane];
                    if (hi == 0 || t + 1 < e) acc4(acc, x2);
                }
            } else {
                for (int t = s; t < e; t += 2) {          // short segment (<=15 rows)
                    float4 x2 = vp[(size_t)t * 32 + lane];
                    if (hi == 0 || t + 1 < e) acc4(acc, x2);
                }
            }
        }
        float4 res = make_float4(0.f, 0.f, 0.f, 0.f);
        if (cnt > 0) {
            acc = xor32_add(acc);                         // fold halves (P diff + SS + edges)
            const float inv = 1.0f / (float)cnt;
            res.x = acc.x * inv; res.y = acc.y * inv;
            res.z = acc.z * inv; res.w = acc.w * inv;
        }
        if (hi == 0)
            ((float4*)(outbase + (pool == 0 ? 0 : 128)))[lane_lo] = res;
    } else {
        const int   T  = 4096;
        const int   NC = T / 8;
        const float r  = 0.25f;
        const int s = min((int)floorf(st * r), T - 1);
        const int e = min((int)ceilf((st + du + kEps) * r), T - 1);
        const int cnt = e - s;

        float4 acc = make_float4(0.f, 0.f, 0.f, 0.f);
        if (cnt > 0) {
            const float4* vp = (const float4*)v2 + (size_t)b * T * 64 + lane;
            const float4* Pb = (const float4*)(ws + P2_OFF) + (size_t)b * NC * 64 + lane;
            const int cs = (s + 7) >> 3;
            const int ce = e >> 3;
            if (ce > cs) {
                acc = Pb[(size_t)(ce - 1) * 64];          // prefix within superchunk of ce-1
                const int jq = cs & 3;
                if (jq) sub4(acc, Pb[(size_t)(cs - 1) * 64]);
                int m  = cs >> 2;
                const int me = (ce - 1) >> 2;
                for (; m < me; ++m)                       // middle SS[m] = P[4m+3], <=3 iters
                    acc4(acc, Pb[(size_t)(m * 4 + 3) * 64]);
                for (int t = s; t < (cs << 3); ++t) acc4(acc, vp[(size_t)t * 64]);
                for (int t = (ce << 3); t < e; ++t) acc4(acc, vp[(size_t)t * 64]);
            } else {
                for (int t = s; t < e; ++t) acc4(acc, vp[(size_t)t * 64]);
            }
        }
        float4 res = make_float4(0.f, 0.f, 0.f, 0.f);
        if (cnt > 0) {
            const float inv = 1.0f / (float)cnt;
            res.x = acc.x * inv; res.y = acc.y * inv;
            res.z = acc.z * inv; res.w = acc.w * inv;
        }
        ((float4*)(outbase + 256))[lane] = res;
    }
}

extern "C" void kernel_launch(void* const* d_in, const int* in_sizes, int n_in,
                              void* d_out, int out_size, void* d_ws, size_t ws_size,
                              hipStream_t stream) {
    const float* v0    = (const float*)d_in[0];
    const float* v1    = (const float*)d_in[1];
    const float* v2    = (const float*)d_in[2];
    const float* start = (const float*)d_in[3];
    const float* dur   = (const float*)d_in[4];
    float*       out   = (float*)d_out;
    float*       ws    = (float*)d_ws;

    // Pass 1: 4096 waves (2048 + 1024 + 1024), 4 waves/block
    prefix_kernel<<<dim3(4096 / 4), 256, 0, stream>>>(v0, v1, v2, ws);
    // Pass 2: one wave per (bn, pool)
    gather_kernel<<<dim3(kB * kN / 4, 3), 256, 0, stream>>>(v0, v1, v2, start, dur, ws, out);
}